// Round 3
// baseline (581.421 us; speedup 1.0000x reference)
//
#include <hip/hip_runtime.h>
#include <hip/hip_bf16.h>

// RNN wavefunction log-prob: N=128 steps, B=8192, H=128, D=2 (one-hot).
// R10: occupancy experiment. R9's 4-wave high-ILP block (wave owns 32
// hidden rows) was grid-limited to 2 blocks/CU. Here: 1024 blocks x 256
// threads, 8 REAL samples per block (tile stays 16 wide; upper half of
// MFMA N-dim is garbage -- MFMA pipe is ~7% busy, waste is free).
// 4 blocks/CU = 16 waves/CU in 4 independent barrier groups.
// fw (dense head) moved to LDS to guarantee <=128 VGPR (R9 spilled 184B/thr).

#define NSTEP 128
#define BTOT  8192
#define HID   128
#define MBR   8             // real samples per block
#define MB    16            // tile width (MFMA N)
#define NBLK  (BTOT / MBR)  // 1024
#define NTHR  256

typedef __attribute__((ext_vector_type(8))) short bf16x8;
typedef __attribute__((ext_vector_type(4))) float f32x4;
typedef __attribute__((ext_vector_type(2))) float f32x2;
typedef __attribute__((ext_vector_type(2))) unsigned uint32x2;

__device__ __forceinline__ short f2bf(float v) {
    unsigned u = __builtin_bit_cast(unsigned, v);
    u += 0x7FFFu + ((u >> 16) & 1u);
    return (short)(u >> 16);
}
// two f32 -> packed bf16x2
__device__ __forceinline__ unsigned cvt2bf(float a, float b) {
    __hip_bfloat162 h2 = __float22bfloat162_rn(make_float2(a, b));
    unsigned u; __builtin_memcpy(&u, &h2, sizeof(u));
    return u;
}
// tanh pair, independent rcp (short dep chain)
__device__ __forceinline__ f32x2 tanh2(f32x2 x) {
    f32x2 z = x * 2.885390081777927f;            // 2x*log2(e)
    float r0 = __builtin_amdgcn_rcpf(__builtin_exp2f(z.x) + 1.0f);
    float r1 = __builtin_amdgcn_rcpf(__builtin_exp2f(z.y) + 1.0f);
    f32x2 r = {r0, r1};
    return r * -2.0f + 1.0f;                     // 1 - 2/(e^2x+1)
}

__global__ __launch_bounds__(NTHR, 4) void rnn_wf_kernel(
    const float* __restrict__ samples,  // (128, 8192, 2)
    const float* __restrict__ Wih0,     // (128, 2)
    const float* __restrict__ bih0,     // (128,)
    const float* __restrict__ Whh0,     // (128, 128)
    const float* __restrict__ bhh0,     // (128,)
    const float* __restrict__ Wih1,     // (128, 128)
    const float* __restrict__ bih1,     // (128,)
    const float* __restrict__ Whh1,     // (128, 128)
    const float* __restrict__ bhh1,     // (128,)
    const float* __restrict__ Wd,       // (2, 128)
    const float* __restrict__ bd,       // (2,)
    float* __restrict__ out)            // (1, 8192)
{
    __shared__ short sH0[2][MB * HID];
    __shared__ short sH1[2][MB * HID];
    __shared__ unsigned sMask[NSTEP];
    __shared__ float sLd[NSTEP * 17];            // logit diffs [t*17 + s]
    __shared__ __attribute__((aligned(16))) float sBias[4 * HID];
    // segments: [0:128)=WA (b0+Wih0 col0), [128:256)=WB (col1),
    //           [256:384)=B1, [384:512)=B0 plain
    __shared__ __attribute__((aligned(16))) short sFwd[4 * 64 * 8];

    const int tid  = threadIdx.x;
    const int b0   = blockIdx.x * MBR;
    const int w    = tid >> 6;          // wave 0..3, owns n in [32w, 32w+32)
    const int lane = tid & 63;
    const int q    = lane >> 4;
    const int c    = lane & 15;

    // ---- decode f32 one-hot samples -> per-step 8-bit masks ----
    if (tid < NSTEP) {
        unsigned msk = 0;
        #pragma unroll
        for (int m = 0; m < MBR; ++m) {
            float e1 = samples[((size_t)tid * BTOT + b0 + m) * 2 + 1];
            if (e1 > 0.5f) msk |= (1u << m);
        }
        sMask[tid] = msk;
    }
    // ---- biases into LDS ----
    if (tid >= NSTEP) {                 // tid in [128,256)
        const int n = tid - NSTEP;
        const float bb = bih0[n] + bhh0[n];
        sBias[n]       = bb + Wih0[n * 2 + 0];
        sBias[128 + n] = bb + Wih0[n * 2 + 1];
        sBias[256 + n] = bih1[n] + bhh1[n];
        sBias[384 + n] = bb;
    }
    // ---- dense-head fragments into LDS (all 256 threads) ----
    {
        const int kb = tid >> 6, l = tid & 63, cc = l & 15, qq = l >> 4;
        bf16x8 v;
        #pragma unroll
        for (int j = 0; j < 8; ++j)
            v[j] = (cc < 2) ? f2bf(Wd[cc * HID + kb * 32 + qq * 8 + j]) : (short)0;
        *reinterpret_cast<bf16x8*>(&sFwd[(kb * 64 + l) * 8]) = v;
    }

    // ---- weight A-fragments in registers: lane holds W[32w+16t+c][kb*32+q*8 ..+8]
    bf16x8 fhh0[2][4], fih1[2][4], fhh1[2][4];
    {
        auto ldf = [](const float* p) {
            f32x4 l0 = *reinterpret_cast<const f32x4*>(p);
            f32x4 l1 = *reinterpret_cast<const f32x4*>(p + 4);
            bf16x8 v;
            v[0]=f2bf(l0[0]); v[1]=f2bf(l0[1]); v[2]=f2bf(l0[2]); v[3]=f2bf(l0[3]);
            v[4]=f2bf(l1[0]); v[5]=f2bf(l1[1]); v[6]=f2bf(l1[2]); v[7]=f2bf(l1[3]);
            return v;
        };
        #pragma unroll
        for (int t = 0; t < 2; ++t) {
            const int nn = w * 32 + t * 16 + c;
            #pragma unroll
            for (int kb = 0; kb < 4; ++kb) {
                const int off = nn * HID + kb * 32 + q * 8;
                fhh0[t][kb] = ldf(Whh0 + off);
                fih1[t][kb] = ldf(Wih1 + off);
                fhh1[t][kb] = ldf(Whh1 + off);
            }
        }
    }
    const float bd0 = bd[0], bd1 = bd[1];

    // ---- t-invariant LDS indices ----
    int ra[4];
    #pragma unroll
    for (int kb = 0; kb < 4; ++kb)
        ra[kb] = c * HID + (((kb * 4 + q) ^ c) << 3);
    // write: h'[m=c][n = 32w + 16t + 4q + r]; 8-block = 4w+2t+(q>>1), half q&1
    int wa[2];
    #pragma unroll
    for (int t = 0; t < 2; ++t)
        wa[t] = c * HID + (((4 * w + 2 * t + (q >> 1)) ^ c) << 3) + ((q & 1) << 2);
    const int ib0 = w * 32 + q * 4;        // float index into bias segments, t=0
    const int ib1 = w * 32 + 16 + q * 4;   // t=1

    bool bmPrev = false;

    auto storeT = [&](short* buf, int t, const f32x4& a) {
        f32x2 t0 = tanh2((f32x2){a[0], a[1]});
        f32x2 t1 = tanh2((f32x2){a[2], a[3]});
        uint32x2 v = {cvt2bf(t0.x, t0.y), cvt2bf(t1.x, t1.y)};
        *reinterpret_cast<uint32x2*>(&buf[t ? wa[1] : wa[0]]) = v;
    };

    __syncthreads();                 // sMask, sBias, sFwd published

    // ---- i = 0: h0(0) = tanh(b0) ----
    storeT(sH0[1], 0, *reinterpret_cast<const f32x4*>(&sBias[384 + ib0]));
    storeT(sH0[1], 1, *reinterpret_cast<const f32x4*>(&sBias[384 + ib1]));
    __syncthreads();

    // ---- i = 1: h0(1), h1(0) ----
    {
        const bool bmIn = (sMask[0] >> c) & 1u;
        const float* bp = bmIn ? (sBias + 128) : sBias;
        f32x4 a0[2], a1[2];
        a0[0] = *reinterpret_cast<const f32x4*>(&bp[ib0]);
        a0[1] = *reinterpret_cast<const f32x4*>(&bp[ib1]);
        a1[0] = *reinterpret_cast<const f32x4*>(&sBias[256 + ib0]);
        a1[1] = *reinterpret_cast<const f32x4*>(&sBias[256 + ib1]);
        #pragma unroll
        for (int kb = 0; kb < 4; ++kb) {
            bf16x8 f0 = *reinterpret_cast<const bf16x8*>(&sH0[1][ra[kb]]);
            a0[0] = __builtin_amdgcn_mfma_f32_16x16x32_bf16(fhh0[0][kb], f0, a0[0], 0, 0, 0);
            a0[1] = __builtin_amdgcn_mfma_f32_16x16x32_bf16(fhh0[1][kb], f0, a0[1], 0, 0, 0);
            a1[0] = __builtin_amdgcn_mfma_f32_16x16x32_bf16(fih1[0][kb], f0, a1[0], 0, 0, 0);
            a1[1] = __builtin_amdgcn_mfma_f32_16x16x32_bf16(fih1[1][kb], f0, a1[1], 0, 0, 0);
        }
        storeT(sH0[0], 0, a0[0]); storeT(sH0[0], 1, a0[1]);
        storeT(sH1[0], 0, a1[0]); storeT(sH1[0], 1, a1[1]);
        bmPrev = bmIn;
        __syncthreads();
    }

    // ---- main: i = 2..127, one barrier per iteration ----
    auto stepMain = [&](int i, const short* r0, const short* r1,
                        short* w0b, short* w1b) {
        const bool bmIn = (sMask[i - 1] >> c) & 1u;
        const float* bp = bmIn ? (sBias + 128) : sBias;
        f32x4 a0[2], a1[2];
        a0[0] = *reinterpret_cast<const f32x4*>(&bp[ib0]);
        a0[1] = *reinterpret_cast<const f32x4*>(&bp[ib1]);
        a1[0] = *reinterpret_cast<const f32x4*>(&sBias[256 + ib0]);
        a1[1] = *reinterpret_cast<const f32x4*>(&sBias[256 + ib1]);
        bf16x8 f1[4];
        #pragma unroll
        for (int kb = 0; kb < 4; ++kb)
            f1[kb] = *reinterpret_cast<const bf16x8*>(&r1[ra[kb]]);
        #pragma unroll
        for (int kb = 0; kb < 4; ++kb) {
            bf16x8 f0 = *reinterpret_cast<const bf16x8*>(&r0[ra[kb]]);
            a0[0] = __builtin_amdgcn_mfma_f32_16x16x32_bf16(fhh0[0][kb], f0, a0[0], 0, 0, 0);
            a0[1] = __builtin_amdgcn_mfma_f32_16x16x32_bf16(fhh0[1][kb], f0, a0[1], 0, 0, 0);
            a1[0] = __builtin_amdgcn_mfma_f32_16x16x32_bf16(fih1[0][kb], f0, a1[0], 0, 0, 0);
            a1[1] = __builtin_amdgcn_mfma_f32_16x16x32_bf16(fih1[1][kb], f0, a1[1], 0, 0, 0);
            a1[0] = __builtin_amdgcn_mfma_f32_16x16x32_bf16(fhh1[0][kb], f1[kb], a1[0], 0, 0, 0);
            a1[1] = __builtin_amdgcn_mfma_f32_16x16x32_bf16(fhh1[1][kb], f1[kb], a1[1], 0, 0, 0);
        }
        if (w == (i & 3)) {   // rotate logits duty across the 4 waves
            f32x4 aL = {bd0, bd1, 0.f, 0.f};
            #pragma unroll
            for (int kb = 0; kb < 4; ++kb) {
                bf16x8 fw = *reinterpret_cast<const bf16x8*>(&sFwd[(kb * 64 + lane) * 8]);
                aL = __builtin_amdgcn_mfma_f32_16x16x32_bf16(fw, f1[kb], aL, 0, 0, 0);
            }
            if (q == 0)
                sLd[(i - 2) * 17 + c] = bmPrev ? (aL[0] - aL[1]) : (aL[1] - aL[0]);
        }
        bmPrev = bmIn;
        storeT(w0b, 0, a0[0]); storeT(w0b, 1, a0[1]);
        storeT(w1b, 0, a1[0]); storeT(w1b, 1, a1[1]);
        __syncthreads();
    };

    for (int i = 2; i < NSTEP; i += 2) {
        stepMain(i,     sH0[0], sH1[0], sH0[1], sH1[1]);
        stepMain(i + 1, sH0[1], sH1[1], sH0[0], sH1[0]);
    }

    // ---- i = 128: h1(127), logits(126) ----
    {
        f32x4 a1[2];
        a1[0] = *reinterpret_cast<const f32x4*>(&sBias[256 + ib0]);
        a1[1] = *reinterpret_cast<const f32x4*>(&sBias[256 + ib1]);
        bf16x8 f1[4];
        #pragma unroll
        for (int kb = 0; kb < 4; ++kb)
            f1[kb] = *reinterpret_cast<const bf16x8*>(&sH1[0][ra[kb]]);  // h1(126)
        #pragma unroll
        for (int kb = 0; kb < 4; ++kb) {
            bf16x8 f0 = *reinterpret_cast<const bf16x8*>(&sH0[0][ra[kb]]);  // h0(127)
            a1[0] = __builtin_amdgcn_mfma_f32_16x16x32_bf16(fhh1[0][kb], f1[kb], a1[0], 0, 0, 0);
            a1[1] = __builtin_amdgcn_mfma_f32_16x16x32_bf16(fhh1[1][kb], f1[kb], a1[1], 0, 0, 0);
            a1[0] = __builtin_amdgcn_mfma_f32_16x16x32_bf16(fih1[0][kb], f0, a1[0], 0, 0, 0);
            a1[1] = __builtin_amdgcn_mfma_f32_16x16x32_bf16(fih1[1][kb], f0, a1[1], 0, 0, 0);
        }
        if (w == 0) {         // 128 & 3 == 0, keeps the rotation
            f32x4 aL = {bd0, bd1, 0.f, 0.f};
            #pragma unroll
            for (int kb = 0; kb < 4; ++kb) {
                bf16x8 fw = *reinterpret_cast<const bf16x8*>(&sFwd[(kb * 64 + lane) * 8]);
                aL = __builtin_amdgcn_mfma_f32_16x16x32_bf16(fw, f1[kb], aL, 0, 0, 0);
            }
            if (q == 0)
                sLd[126 * 17 + c] = bmPrev ? (aL[0] - aL[1]) : (aL[1] - aL[0]);
        }
        storeT(sH1[1], 0, a1[0]); storeT(sH1[1], 1, a1[1]);
        __syncthreads();
    }
    // ---- i = 129: logits(127), wave 1 ----
    if (w == 1) {
        f32x4 aL = {bd0, bd1, 0.f, 0.f};
        #pragma unroll
        for (int kb = 0; kb < 4; ++kb) {
            bf16x8 f1 = *reinterpret_cast<const bf16x8*>(&sH1[1][ra[kb]]);
            bf16x8 fw = *reinterpret_cast<const bf16x8*>(&sFwd[(kb * 64 + lane) * 8]);
            aL = __builtin_amdgcn_mfma_f32_16x16x32_bf16(fw, f1, aL, 0, 0, 0);
        }
        if (q == 0) {
            const bool bit = (sMask[NSTEP - 1] >> c) & 1u;
            sLd[127 * 17 + c] = bit ? (aL[0] - aL[1]) : (aL[1] - aL[0]);
        }
    }
    __syncthreads();

    // ---- final pass: lp(s) = sum_t -log(1 + exp(diff_t)) ----
    if (tid < MBR * 16) {
        const int s = tid >> 4;       // sample 0..7
        const int k = tid & 15;       // step sub-index
        float acc = 0.0f;
        #pragma unroll
        for (int j = 0; j < 8; ++j) {
            const float x = sLd[(j * 16 + k) * 17 + s];
            const float ed = __builtin_exp2f(x * 1.4426950408889634f);
            acc -= 0.6931471805599453f * __builtin_log2f(1.0f + ed);
        }
        #pragma unroll
        for (int off = 1; off < 16; off <<= 1)
            acc += __shfl_xor(acc, off, 64);
        if (k == 0)
            out[b0 + s] = acc;
    }
}

extern "C" void kernel_launch(void* const* d_in, const int* in_sizes, int n_in,
                              void* d_out, int out_size, void* d_ws, size_t ws_size,
                              hipStream_t stream) {
    rnn_wf_kernel<<<NBLK, NTHR, 0, stream>>>(
        (const float*)d_in[0],  // samples
        (const float*)d_in[1],  // W_ih0
        (const float*)d_in[2],  // b_ih0
        (const float*)d_in[3],  // W_hh0
        (const float*)d_in[4],  // b_hh0
        (const float*)d_in[5],  // W_ih1
        (const float*)d_in[6],  // b_ih1
        (const float*)d_in[7],  // W_hh1
        (const float*)d_in[8],  // b_hh1
        (const float*)d_in[9],  // W_dense
        (const float*)d_in[10], // b_dense
        (float*)d_out);
}

// Round 4
// 392.189 us; speedup vs baseline: 1.4825x; 1.4825x over previous
//
#include <hip/hip_runtime.h>
#include <hip/hip_bf16.h>

// RNN wavefunction log-prob: N=128 steps, B=8192, H=128, D=2 (one-hot).
// R11: TLP test on the PROVEN R7 codegen (8 waves, 16 rows/wave, VGPR=64,
// no spill). Only change: grid 1024 x 8 REAL samples per block (tile stays
// 16 wide; upper 8 MFMA columns are garbage -- MFMA pipe ~23% busy, waste
// is free). VGPR=64 + 31KB LDS => 4 blocks/CU = 4 independent barrier
// chains = 32 waves/CU, vs R7's 2. Tests latency- vs LDS-pipe-bound:
// expect ~140us if latency-bound, >230us if LDS-pipe-bound.
// R10's 4-wave variant hit compiler remat (VGPR 64, FETCH 243MB) - abandoned.

#define NSTEP 128
#define BTOT  8192
#define HID   128
#define MBR   8             // real samples per block
#define MB    16            // tile width (MFMA N)
#define NBLK  (BTOT / MBR)  // 1024
#define NTHR  512

typedef __attribute__((ext_vector_type(8))) short bf16x8;
typedef __attribute__((ext_vector_type(4))) float f32x4;
typedef __attribute__((ext_vector_type(2))) float f32x2;
typedef __attribute__((ext_vector_type(2))) unsigned uint32x2;

__device__ __forceinline__ short f2bf(float v) {
    unsigned u = __builtin_bit_cast(unsigned, v);
    u += 0x7FFFu + ((u >> 16) & 1u);
    return (short)(u >> 16);
}
// two f32 -> packed bf16x2 via v_cvt_pk_bf16_f32
__device__ __forceinline__ unsigned cvt2bf(float a, float b) {
    __hip_bfloat162 h2 = __float22bfloat162_rn(make_float2(a, b));
    unsigned u; __builtin_memcpy(&u, &h2, sizeof(u));
    return u;
}
// tanh on a pair: 2 exp + ONE rcp (shared via rcp(d0*d1))
__device__ __forceinline__ f32x2 tanh2(f32x2 x) {
    f32x2 z = x * 2.885390081777927f;            // 2x*log2(e)
    float e0 = __builtin_exp2f(z.x);
    float e1 = __builtin_exp2f(z.y);
    f32x2 d = {e0 + 1.0f, e1 + 1.0f};
    float r = __builtin_amdgcn_rcpf(d.x * d.y);
    f32x2 inv = {r * d.y, r * d.x};              // 1/d.x, 1/d.y
    return inv * -2.0f + 1.0f;
}

__global__ __launch_bounds__(NTHR, 4) void rnn_wf_kernel(
    const float* __restrict__ samples,  // (128, 8192, 2)
    const float* __restrict__ Wih0,     // (128, 2)
    const float* __restrict__ bih0,     // (128,)
    const float* __restrict__ Whh0,     // (128, 128)
    const float* __restrict__ bhh0,     // (128,)
    const float* __restrict__ Wih1,     // (128, 128)
    const float* __restrict__ bih1,     // (128,)
    const float* __restrict__ Whh1,     // (128, 128)
    const float* __restrict__ bhh1,     // (128,)
    const float* __restrict__ Wd,       // (2, 128)
    const float* __restrict__ bd,       // (2,)
    float* __restrict__ out)            // (1, 8192)
{
    __shared__ short sH0[2][MB * HID];
    __shared__ short sH1[2][MB * HID];
    __shared__ unsigned sMask[NSTEP];
    __shared__ float sLd[NSTEP * 17];            // logit diffs [t*17 + s]
    __shared__ __attribute__((aligned(16))) float sBias[4 * HID];
    // segments: [0:128)=WA (b0+Wih0 col0), [128:256)=WB (col1),
    //           [256:384)=B1, [384:512)=B0 plain
    __shared__ __attribute__((aligned(16))) short sFwd[4 * 64 * 8];

    const int tid  = threadIdx.x;
    const int b0   = blockIdx.x * MBR;
    const int w    = tid >> 6;          // wave 0..7, owns n in [16w, 16w+16)
    const int lane = tid & 63;
    const int q    = lane >> 4;
    const int c    = lane & 15;

    // ---- decode f32 one-hot samples -> per-step 8-bit masks ----
    if (tid < NSTEP) {
        unsigned msk = 0;
        #pragma unroll
        for (int m = 0; m < MBR; ++m) {
            float e1 = samples[((size_t)tid * BTOT + b0 + m) * 2 + 1];
            if (e1 > 0.5f) msk |= (1u << m);
        }
        sMask[tid] = msk;
    }
    // ---- biases into LDS ----
    if (tid >= NSTEP && tid < NSTEP + HID) {
        const int n = tid - NSTEP;
        const float bb = bih0[n] + bhh0[n];
        sBias[n]       = bb + Wih0[n * 2 + 0];
        sBias[128 + n] = bb + Wih0[n * 2 + 1];
        sBias[256 + n] = bih1[n] + bhh1[n];
        sBias[384 + n] = bb;
    }
    // ---- dense-head fragments into LDS ----
    if (tid >= 256 && tid < 512) {
        const int t2 = tid - 256;
        const int kb = t2 >> 6, l = t2 & 63, cc = l & 15, qq = l >> 4;
        bf16x8 v;
        #pragma unroll
        for (int j = 0; j < 8; ++j)
            v[j] = (cc < 2) ? f2bf(Wd[cc * HID + kb * 32 + qq * 8 + j]) : (short)0;
        *reinterpret_cast<bf16x8*>(&sFwd[(kb * 64 + l) * 8]) = v;
    }

    // ---- weight A-fragments: lane holds W[16w+c][kb*32+q*8 .. +8] ----
    bf16x8 fhh0[4], fih1[4], fhh1[4];
    {
        const int nn = w * 16 + c;
        #pragma unroll
        for (int kb = 0; kb < 4; ++kb) {
            const int off = nn * HID + kb * 32 + q * 8;
            bf16x8 v0, v1, v2;
            #pragma unroll
            for (int j = 0; j < 8; ++j) {
                v0[j] = f2bf(Whh0[off + j]);
                v1[j] = f2bf(Wih1[off + j]);
                v2[j] = f2bf(Whh1[off + j]);
            }
            fhh0[kb] = v0; fih1[kb] = v1; fhh1[kb] = v2;
        }
    }
    const float bd0 = bd[0], bd1 = bd[1];

    // ---- t-invariant LDS indices ----
    int ra[4];
    #pragma unroll
    for (int kb = 0; kb < 4; ++kb)
        ra[kb] = c * HID + (((kb * 4 + q) ^ c) << 3);
    // write: h'[m=c][n = 16w + 4q + r]; 8-block = 2w + (q>>1), half q&1
    const int wa = c * HID + (((2 * w + (q >> 1)) ^ c) << 3) + ((q & 1) << 2);
    const int ib = w * 16 + q * 4;   // float index into bias arrays

    bool bmPrev = false;

    // write one layer's 4 tanh'd values (b64)
    auto storeL = [&](short* buf, const f32x4& a) {
        f32x2 t0 = tanh2((f32x2){a[0], a[1]});
        f32x2 t1 = tanh2((f32x2){a[2], a[3]});
        uint32x2 v = {cvt2bf(t0.x, t0.y), cvt2bf(t1.x, t1.y)};
        *reinterpret_cast<uint32x2*>(&buf[wa]) = v;
    };

    __syncthreads();                 // sMask, sBias, sFwd published

    // ---- i = 0: h0(0) = tanh(b0) ----
    storeL(sH0[1], *reinterpret_cast<const f32x4*>(&sBias[384 + ib]));
    __syncthreads();

    // ---- i = 1: h0(1), h1(0) ----
    {
        const bool bmIn = (sMask[0] >> c) & 1u;
        const float* bp = bmIn ? (sBias + 128) : sBias;
        f32x4 a0 = *reinterpret_cast<const f32x4*>(&bp[ib]);
        f32x4 a1 = *reinterpret_cast<const f32x4*>(&sBias[256 + ib]);
        #pragma unroll
        for (int kb = 0; kb < 4; ++kb) {
            bf16x8 f0 = *reinterpret_cast<const bf16x8*>(&sH0[1][ra[kb]]);
            a0 = __builtin_amdgcn_mfma_f32_16x16x32_bf16(fhh0[kb], f0, a0, 0, 0, 0);
            a1 = __builtin_amdgcn_mfma_f32_16x16x32_bf16(fih1[kb], f0, a1, 0, 0, 0);
        }
        storeL(sH0[0], a0);   // h0(1)
        storeL(sH1[0], a1);   // h1(0)
        bmPrev = bmIn;
        __syncthreads();
    }

    // ---- main: i = 2..127, one barrier per iteration ----
    auto stepMain = [&](int i, const short* r0, const short* r1,
                        short* w0b, short* w1b) {
        const bool bmIn = (sMask[i - 1] >> c) & 1u;
        const float* bp = bmIn ? (sBias + 128) : sBias;
        f32x4 a0 = *reinterpret_cast<const f32x4*>(&bp[ib]);
        f32x4 a1 = *reinterpret_cast<const f32x4*>(&sBias[256 + ib]);
        bf16x8 f0[4], f1[4];
        #pragma unroll
        for (int kb = 0; kb < 4; ++kb) {
            f0[kb] = *reinterpret_cast<const bf16x8*>(&r0[ra[kb]]);
            f1[kb] = *reinterpret_cast<const bf16x8*>(&r1[ra[kb]]);
        }
        #pragma unroll
        for (int kb = 0; kb < 4; ++kb) {
            a0 = __builtin_amdgcn_mfma_f32_16x16x32_bf16(fhh0[kb], f0[kb], a0, 0, 0, 0);
            a1 = __builtin_amdgcn_mfma_f32_16x16x32_bf16(fhh1[kb], f1[kb], a1, 0, 0, 0);
        }
        #pragma unroll
        for (int kb = 0; kb < 4; ++kb)
            a1 = __builtin_amdgcn_mfma_f32_16x16x32_bf16(fih1[kb], f0[kb], a1, 0, 0, 0);
        if (w == (i & 7)) {   // rotate logits duty across the 8 waves
            f32x4 aL = {bd0, bd1, 0.f, 0.f};
            #pragma unroll
            for (int kb = 0; kb < 4; ++kb) {
                bf16x8 fw = *reinterpret_cast<const bf16x8*>(&sFwd[(kb * 64 + lane) * 8]);
                aL = __builtin_amdgcn_mfma_f32_16x16x32_bf16(fw, f1[kb], aL, 0, 0, 0);
            }
            if (q == 0)
                sLd[(i - 2) * 17 + c] = bmPrev ? (aL[0] - aL[1]) : (aL[1] - aL[0]);
        }
        bmPrev = bmIn;
        storeL(w0b, a0);              // h0(i)
        storeL(w1b, a1);              // h1(i-1)
        __syncthreads();
    };

    for (int i = 2; i < NSTEP; i += 2) {
        stepMain(i,     sH0[0], sH1[0], sH0[1], sH1[1]);
        stepMain(i + 1, sH0[1], sH1[1], sH0[0], sH1[0]);
    }

    // ---- i = 128: h1(127), logits(126) ----
    {
        f32x4 a1 = *reinterpret_cast<const f32x4*>(&sBias[256 + ib]);
        bf16x8 f0[4], f1[4];
        #pragma unroll
        for (int kb = 0; kb < 4; ++kb) {
            f0[kb] = *reinterpret_cast<const bf16x8*>(&sH0[0][ra[kb]]);  // h0(127)
            f1[kb] = *reinterpret_cast<const bf16x8*>(&sH1[0][ra[kb]]);  // h1(126)
        }
        #pragma unroll
        for (int kb = 0; kb < 4; ++kb)
            a1 = __builtin_amdgcn_mfma_f32_16x16x32_bf16(fhh1[kb], f1[kb], a1, 0, 0, 0);
        #pragma unroll
        for (int kb = 0; kb < 4; ++kb)
            a1 = __builtin_amdgcn_mfma_f32_16x16x32_bf16(fih1[kb], f0[kb], a1, 0, 0, 0);
        if (w == 0) {
            f32x4 aL = {bd0, bd1, 0.f, 0.f};
            #pragma unroll
            for (int kb = 0; kb < 4; ++kb) {
                bf16x8 fw = *reinterpret_cast<const bf16x8*>(&sFwd[(kb * 64 + lane) * 8]);
                aL = __builtin_amdgcn_mfma_f32_16x16x32_bf16(fw, f1[kb], aL, 0, 0, 0);
            }
            if (q == 0)
                sLd[126 * 17 + c] = bmPrev ? (aL[0] - aL[1]) : (aL[1] - aL[0]);
        }
        storeL(sH1[1], a1);           // h1(127)
        __syncthreads();
    }
    // ---- i = 129: logits(127), wave 1 ----
    if (w == 1) {
        f32x4 aL = {bd0, bd1, 0.f, 0.f};
        #pragma unroll
        for (int kb = 0; kb < 4; ++kb) {
            bf16x8 f1 = *reinterpret_cast<const bf16x8*>(&sH1[1][ra[kb]]);
            bf16x8 fw = *reinterpret_cast<const bf16x8*>(&sFwd[(kb * 64 + lane) * 8]);
            aL = __builtin_amdgcn_mfma_f32_16x16x32_bf16(fw, f1, aL, 0, 0, 0);
        }
        if (q == 0) {
            const bool bit = (sMask[NSTEP - 1] >> c) & 1u;
            sLd[127 * 17 + c] = bit ? (aL[0] - aL[1]) : (aL[1] - aL[0]);
        }
    }
    __syncthreads();

    // ---- final pass: lp(s) = sum_t -log(1 + exp(diff_t)) ----
    if (tid < MBR * 16) {
        const int s = tid >> 4;       // sample 0..7
        const int k = tid & 15;       // step sub-index
        float acc = 0.0f;
        #pragma unroll
        for (int j = 0; j < 8; ++j) {
            const float x = sLd[(j * 16 + k) * 17 + s];
            const float ed = __builtin_exp2f(x * 1.4426950408889634f);
            acc -= 0.6931471805599453f * __builtin_log2f(1.0f + ed);
        }
        #pragma unroll
        for (int off = 1; off < 16; off <<= 1)
            acc += __shfl_xor(acc, off, 64);
        if (k == 0)
            out[b0 + s] = acc;
    }
}

extern "C" void kernel_launch(void* const* d_in, const int* in_sizes, int n_in,
                              void* d_out, int out_size, void* d_ws, size_t ws_size,
                              hipStream_t stream) {
    rnn_wf_kernel<<<NBLK, NTHR, 0, stream>>>(
        (const float*)d_in[0],  // samples
        (const float*)d_in[1],  // W_ih0
        (const float*)d_in[2],  // b_ih0
        (const float*)d_in[3],  // W_hh0
        (const float*)d_in[4],  // b_hh0
        (const float*)d_in[5],  // W_ih1
        (const float*)d_in[6],  // b_ih1
        (const float*)d_in[7],  // W_hh1
        (const float*)d_in[8],  // b_hh1
        (const float*)d_in[9],  // W_dense
        (const float*)d_in[10], // b_dense
        (float*)d_out);
}

// Round 5
// 268.056 us; speedup vs baseline: 2.1690x; 1.4631x over previous
//
#include <hip/hip_runtime.h>
#include <hip/hip_bf16.h>

// RNN wavefunction log-prob: N=128 steps, B=8192, H=128, D=2 (one-hot).
// R12: shrink the per-step interval (R9/R11 proved parallelism is not a
// lever: ~1850cy/block-step invariant under 2x waves or 2x blocks).
// Proven R7 8-wave structure, grid 512x16. Deltas:
//  1) per-step mask ds_read -> per-thread 64-bit reg pair (shift per pair)
//  2) biases -> regs (cndmask select), -2 b128 LDS reads per wave-step
//  3) MFMA accumulation chains split (a1: 8-deep -> 4+4, a0: 4 -> 2+2)
// Watch: VGPR must stay <=128 (2 blocks/CU needs 4 waves/SIMD).

#define NSTEP 128
#define BTOT  8192
#define HID   128
#define MB    16
#define NBLK  (BTOT / MB)   // 512
#define NTHR  512

typedef __attribute__((ext_vector_type(8))) short bf16x8;
typedef __attribute__((ext_vector_type(4))) float f32x4;
typedef __attribute__((ext_vector_type(2))) float f32x2;
typedef __attribute__((ext_vector_type(2))) unsigned uint32x2;
typedef __attribute__((ext_vector_type(4))) unsigned uint32x4;
typedef unsigned long long u64;

__device__ __forceinline__ short f2bf(float v) {
    unsigned u = __builtin_bit_cast(unsigned, v);
    u += 0x7FFFu + ((u >> 16) & 1u);
    return (short)(u >> 16);
}
// two f32 -> packed bf16x2 via v_cvt_pk_bf16_f32
__device__ __forceinline__ unsigned cvt2bf(float a, float b) {
    __hip_bfloat162 h2 = __float22bfloat162_rn(make_float2(a, b));
    unsigned u; __builtin_memcpy(&u, &h2, sizeof(u));
    return u;
}
// tanh on a pair: 2 exp + ONE rcp (shared via rcp(d0*d1))
__device__ __forceinline__ f32x2 tanh2(f32x2 x) {
    f32x2 z = x * 2.885390081777927f;            // 2x*log2(e)
    float e0 = __builtin_exp2f(z.x);
    float e1 = __builtin_exp2f(z.y);
    f32x2 d = {e0 + 1.0f, e1 + 1.0f};
    float r = __builtin_amdgcn_rcpf(d.x * d.y);
    f32x2 inv = {r * d.y, r * d.x};              // 1/d.x, 1/d.y
    return inv * -2.0f + 1.0f;
}

__global__ __launch_bounds__(NTHR, 4) void rnn_wf_kernel(
    const float* __restrict__ samples,  // (128, 8192, 2)
    const float* __restrict__ Wih0,     // (128, 2)
    const float* __restrict__ bih0,     // (128,)
    const float* __restrict__ Whh0,     // (128, 128)
    const float* __restrict__ bhh0,     // (128,)
    const float* __restrict__ Wih1,     // (128, 128)
    const float* __restrict__ bih1,     // (128,)
    const float* __restrict__ Whh1,     // (128, 128)
    const float* __restrict__ bhh1,     // (128,)
    const float* __restrict__ Wd,       // (2, 128)
    const float* __restrict__ bd,       // (2,)
    float* __restrict__ out)            // (1, 8192)
{
    __shared__ short sH0[2][MB * HID];
    __shared__ short sH1[2][MB * HID];
    __shared__ float sLd[NSTEP * 17];            // logit diffs [t*17 + s]
    __shared__ __attribute__((aligned(16))) short sFwd[4 * 64 * 8];
    __shared__ __attribute__((aligned(16))) unsigned sWords[16][4]; // per-sample step bits

    const int tid  = threadIdx.x;
    const int b0   = blockIdx.x * MB;
    const int w    = tid >> 6;          // wave 0..7, owns n in [16w, 16w+16)
    const int lane = tid & 63;
    const int q    = lane >> 4;
    const int c    = lane & 15;

    // ---- decode one-hot samples -> per-sample 32-bit step words ----
    if (tid < 64) {
        const int j = tid >> 4;         // word 0..3 (steps 32j..32j+31)
        const int s = tid & 15;         // sample
        unsigned word = 0;
        #pragma unroll
        for (int tt = 0; tt < 32; ++tt) {
            float e1 = samples[((size_t)(j * 32 + tt) * BTOT + b0 + s) * 2 + 1];
            if (e1 > 0.5f) word |= (1u << tt);
        }
        sWords[s][j] = word;
    }
    // ---- dense-head fragments into LDS ----
    if (tid >= 256 && tid < 512) {
        const int t2 = tid - 256;
        const int kb = t2 >> 6, l = t2 & 63, cc = l & 15, qq = l >> 4;
        bf16x8 v;
        #pragma unroll
        for (int j = 0; j < 8; ++j)
            v[j] = (cc < 2) ? f2bf(Wd[cc * HID + kb * 32 + qq * 8 + j]) : (short)0;
        *reinterpret_cast<bf16x8*>(&sFwd[(kb * 64 + l) * 8]) = v;
    }

    // ---- weight A-fragments: lane holds W[16w+c][kb*32+q*8 .. +8] ----
    bf16x8 fhh0[4], fih1[4], fhh1[4];
    {
        const int nn = w * 16 + c;
        #pragma unroll
        for (int kb = 0; kb < 4; ++kb) {
            const int off = nn * HID + kb * 32 + q * 8;
            bf16x8 v0, v1, v2;
            #pragma unroll
            for (int j = 0; j < 8; ++j) {
                v0[j] = f2bf(Whh0[off + j]);
                v1[j] = f2bf(Wih1[off + j]);
                v2[j] = f2bf(Whh1[off + j]);
            }
            fhh0[kb] = v0; fih1[kb] = v1; fhh1[kb] = v2;
        }
    }
    const float bd0 = bd[0], bd1 = bd[1];

    // ---- biases in registers for this thread's 4 acc rows ----
    f32x4 bWA, bWB, bB1, bb;
    {
        const int n0 = w * 16 + q * 4;
        f32x4 vi = *reinterpret_cast<const f32x4*>(&bih0[n0]);
        f32x4 vh = *reinterpret_cast<const f32x4*>(&bhh0[n0]);
        bb = vi + vh;
        f32x4 wA = *reinterpret_cast<const f32x4*>(&Wih0[n0 * 2]);      // rows n0,n0+1
        f32x4 wB = *reinterpret_cast<const f32x4*>(&Wih0[n0 * 2 + 4]);  // rows n0+2,n0+3
        bWA = bb + (f32x4){wA[0], wA[2], wB[0], wB[2]};  // + Wih0[:,0]
        bWB = bb + (f32x4){wA[1], wA[3], wB[1], wB[3]};  // + Wih0[:,1]
        f32x4 v1 = *reinterpret_cast<const f32x4*>(&bih1[n0]);
        f32x4 v2 = *reinterpret_cast<const f32x4*>(&bhh1[n0]);
        bB1 = v1 + v2;
    }

    // ---- t-invariant LDS indices ----
    int ra[4];
    #pragma unroll
    for (int kb = 0; kb < 4; ++kb)
        ra[kb] = c * HID + (((kb * 4 + q) ^ c) << 3);
    // write: h'[m=c][n = 16w + 4q + r]; 8-block = 2w + (q>>1), half q&1
    const int wa = c * HID + (((2 * w + (q >> 1)) ^ c) << 3) + ((q & 1) << 2);

    bool bmPrev = false;

    // write one layer's 4 tanh'd values (b64)
    auto storeL = [&](short* buf, const f32x4& a) {
        f32x2 t0 = tanh2((f32x2){a[0], a[1]});
        f32x2 t1 = tanh2((f32x2){a[2], a[3]});
        uint32x2 v = {cvt2bf(t0.x, t0.y), cvt2bf(t1.x, t1.y)};
        *reinterpret_cast<uint32x2*>(&buf[wa]) = v;
    };

    __syncthreads();                 // sWords, sFwd published

    // ---- per-thread mask bits: this lane's sample-c step bits ----
    u64 mlo, mhi;
    {
        const uint32x4 mv = *reinterpret_cast<const uint32x4*>(&sWords[c][0]);
        mlo = (u64)mv[0] | ((u64)mv[1] << 32);
        mhi = (u64)mv[2] | ((u64)mv[3] << 32);
    }

    // ---- i = 0: h0(0) = tanh(b0) ----
    storeL(sH0[1], bb);
    __syncthreads();

    // ---- i = 1: h0(1), h1(0) ----
    {
        const bool bmIn = (mlo & 1ull) != 0;
        f32x4 a0, a1;
        #pragma unroll
        for (int k = 0; k < 4; ++k) a0[k] = bmIn ? bWB[k] : bWA[k];
        a1 = bB1;
        #pragma unroll
        for (int kb = 0; kb < 4; ++kb) {
            bf16x8 f0 = *reinterpret_cast<const bf16x8*>(&sH0[1][ra[kb]]);
            a0 = __builtin_amdgcn_mfma_f32_16x16x32_bf16(fhh0[kb], f0, a0, 0, 0, 0);
            a1 = __builtin_amdgcn_mfma_f32_16x16x32_bf16(fih1[kb], f0, a1, 0, 0, 0);
        }
        storeL(sH0[0], a0);   // h0(1)
        storeL(sH1[0], a1);   // h1(0)
        bmPrev = bmIn;
        __syncthreads();
    }

    // ---- main: i = 2..127, one barrier per iteration ----
    auto stepMain = [&](int i, bool bmIn, const short* r0, const short* r1,
                        short* w0b, short* w1b) {
        f32x4 a0a, a0b, a1a, a1b;
        #pragma unroll
        for (int k = 0; k < 4; ++k) a0a[k] = bmIn ? bWB[k] : bWA[k];
        a0b = (f32x4){0.f, 0.f, 0.f, 0.f};
        a1a = bB1;
        a1b = (f32x4){0.f, 0.f, 0.f, 0.f};
        bf16x8 f0[4], f1[4];
        #pragma unroll
        for (int kb = 0; kb < 4; ++kb) {
            f0[kb] = *reinterpret_cast<const bf16x8*>(&r0[ra[kb]]);
            f1[kb] = *reinterpret_cast<const bf16x8*>(&r1[ra[kb]]);
        }
        // layer-0: two independent 2-chains
        a0a = __builtin_amdgcn_mfma_f32_16x16x32_bf16(fhh0[0], f0[0], a0a, 0, 0, 0);
        a0b = __builtin_amdgcn_mfma_f32_16x16x32_bf16(fhh0[2], f0[2], a0b, 0, 0, 0);
        a0a = __builtin_amdgcn_mfma_f32_16x16x32_bf16(fhh0[1], f0[1], a0a, 0, 0, 0);
        a0b = __builtin_amdgcn_mfma_f32_16x16x32_bf16(fhh0[3], f0[3], a0b, 0, 0, 0);
        // layer-1: two independent 4-chains
        #pragma unroll
        for (int kb = 0; kb < 4; ++kb) {
            a1a = __builtin_amdgcn_mfma_f32_16x16x32_bf16(fhh1[kb], f1[kb], a1a, 0, 0, 0);
            a1b = __builtin_amdgcn_mfma_f32_16x16x32_bf16(fih1[kb], f0[kb], a1b, 0, 0, 0);
        }
        f32x4 a0 = a0a + a0b;
        f32x4 a1 = a1a + a1b;
        if (w == (i & 7)) {   // rotate logits duty across the 8 waves
            f32x4 aL = {bd0, bd1, 0.f, 0.f};
            #pragma unroll
            for (int kb = 0; kb < 4; ++kb) {
                bf16x8 fw = *reinterpret_cast<const bf16x8*>(&sFwd[(kb * 64 + lane) * 8]);
                aL = __builtin_amdgcn_mfma_f32_16x16x32_bf16(fw, f1[kb], aL, 0, 0, 0);
            }
            if (q == 0)
                sLd[(i - 2) * 17 + c] = bmPrev ? (aL[0] - aL[1]) : (aL[1] - aL[0]);
        }
        bmPrev = bmIn;
        storeL(w0b, a0);              // h0(i)
        storeL(w1b, a1);              // h1(i-1)
        __syncthreads();
    };

    // first half: i = 2..65 (32 pairs), mask bits 1..64
    {
        u64 run = (mlo >> 1) | (mhi << 63);
        for (int p = 0; p < 32; ++p) {
            const int i = 2 + 2 * p;
            const bool bA = (run & 1ull) != 0;
            const bool bB = (run & 2ull) != 0;
            run >>= 2;
            stepMain(i,     bA, sH0[0], sH1[0], sH0[1], sH1[1]);
            stepMain(i + 1, bB, sH0[1], sH1[1], sH0[0], sH1[0]);
        }
    }
    // second half: i = 66..127 (31 pairs), mask bits 65..126
    {
        u64 run = mhi >> 1;
        for (int p = 0; p < 31; ++p) {
            const int i = 66 + 2 * p;
            const bool bA = (run & 1ull) != 0;
            const bool bB = (run & 2ull) != 0;
            run >>= 2;
            stepMain(i,     bA, sH0[0], sH1[0], sH0[1], sH1[1]);
            stepMain(i + 1, bB, sH0[1], sH1[1], sH0[0], sH1[0]);
        }
    }

    // ---- i = 128: h1(127), logits(126) ----
    {
        f32x4 a1 = bB1;
        bf16x8 f0[4], f1[4];
        #pragma unroll
        for (int kb = 0; kb < 4; ++kb) {
            f0[kb] = *reinterpret_cast<const bf16x8*>(&sH0[0][ra[kb]]);  // h0(127)
            f1[kb] = *reinterpret_cast<const bf16x8*>(&sH1[0][ra[kb]]);  // h1(126)
        }
        #pragma unroll
        for (int kb = 0; kb < 4; ++kb)
            a1 = __builtin_amdgcn_mfma_f32_16x16x32_bf16(fhh1[kb], f1[kb], a1, 0, 0, 0);
        #pragma unroll
        for (int kb = 0; kb < 4; ++kb)
            a1 = __builtin_amdgcn_mfma_f32_16x16x32_bf16(fih1[kb], f0[kb], a1, 0, 0, 0);
        if (w == 0) {
            f32x4 aL = {bd0, bd1, 0.f, 0.f};
            #pragma unroll
            for (int kb = 0; kb < 4; ++kb) {
                bf16x8 fw = *reinterpret_cast<const bf16x8*>(&sFwd[(kb * 64 + lane) * 8]);
                aL = __builtin_amdgcn_mfma_f32_16x16x32_bf16(fw, f1[kb], aL, 0, 0, 0);
            }
            if (q == 0)
                sLd[126 * 17 + c] = bmPrev ? (aL[0] - aL[1]) : (aL[1] - aL[0]);
        }
        storeL(sH1[1], a1);           // h1(127)
        __syncthreads();
    }
    // ---- i = 129: logits(127), wave 1 ----
    if (w == 1) {
        f32x4 aL = {bd0, bd1, 0.f, 0.f};
        #pragma unroll
        for (int kb = 0; kb < 4; ++kb) {
            bf16x8 f1 = *reinterpret_cast<const bf16x8*>(&sH1[1][ra[kb]]);
            bf16x8 fw = *reinterpret_cast<const bf16x8*>(&sFwd[(kb * 64 + lane) * 8]);
            aL = __builtin_amdgcn_mfma_f32_16x16x32_bf16(fw, f1, aL, 0, 0, 0);
        }
        if (q == 0) {
            const bool bit = (mhi >> 63) != 0;
            sLd[127 * 17 + c] = bit ? (aL[0] - aL[1]) : (aL[1] - aL[0]);
        }
    }
    __syncthreads();

    // ---- final pass: lp(s) = sum_t -log(1 + exp(diff_t)) ----
    if (tid < 256) {
        const int s = tid >> 4;       // sample 0..15
        const int k = tid & 15;       // step sub-index
        float acc = 0.0f;
        #pragma unroll
        for (int j = 0; j < 8; ++j) {
            const float x = sLd[(j * 16 + k) * 17 + s];
            const float ed = __builtin_exp2f(x * 1.4426950408889634f);
            acc -= 0.6931471805599453f * __builtin_log2f(1.0f + ed);
        }
        #pragma unroll
        for (int off = 1; off < 16; off <<= 1)
            acc += __shfl_xor(acc, off, 64);
        if (k == 0)
            out[b0 + s] = acc;
    }
}

extern "C" void kernel_launch(void* const* d_in, const int* in_sizes, int n_in,
                              void* d_out, int out_size, void* d_ws, size_t ws_size,
                              hipStream_t stream) {
    rnn_wf_kernel<<<NBLK, NTHR, 0, stream>>>(
        (const float*)d_in[0],  // samples
        (const float*)d_in[1],  // W_ih0
        (const float*)d_in[2],  // b_ih0
        (const float*)d_in[3],  // W_hh0
        (const float*)d_in[4],  // b_hh0
        (const float*)d_in[5],  // W_ih1
        (const float*)d_in[6],  // b_ih1
        (const float*)d_in[7],  // W_hh1
        (const float*)d_in[8],  // b_hh1
        (const float*)d_in[9],  // W_dense
        (const float*)d_in[10], // b_dense
        (float*)d_out);
}